// Round 8
// baseline (2555.012 us; speedup 1.0000x reference)
//
#include <hip/hip_runtime.h>
#include <hip/hip_bf16.h>

#define BT 2048
#define VOC 32000
#define IGN (-100)

typedef __attribute__((ext_vector_type(4))) float f32x4;
typedef __attribute__((ext_vector_type(8))) short s16x8;
typedef __attribute__((ext_vector_type(4))) unsigned int u32x4;

#define AS1 __attribute__((address_space(1)))
#define AS3 __attribute__((address_space(3)))

__device__ __forceinline__ unsigned short f2bf(float f) {
    union { __hip_bfloat16 h; unsigned short u; } c;
    c.h = __float2bfloat16(f);
    return c.u;
}
__device__ __forceinline__ float bf2f(unsigned short u) {
    union { unsigned int u; float f; } c;
    c.u = ((unsigned int)u) << 16;
    return c.f;
}
__device__ __forceinline__ unsigned int pk2(float a, float b) {
    return (unsigned int)f2bf(a) | ((unsigned int)f2bf(b) << 16);
}

// ---------------------------------------------------------------------------
// fp32 -> bf16 pre-convert, row-major (for W)
// ---------------------------------------------------------------------------
__global__ __launch_bounds__(256)
void cvt_kernel(const float* __restrict__ in, unsigned short* __restrict__ out, int n8) {
    for (int i = blockIdx.x * 256 + threadIdx.x; i < n8; i += gridDim.x * 256) {
        f32x4 a = ((const f32x4*)in)[2 * i];
        f32x4 b = ((const f32x4*)in)[2 * i + 1];
        u32x4 o;
        o[0] = pk2(a[0], a[1]);
        o[1] = pk2(a[2], a[3]);
        o[2] = pk2(b[0], b[1]);
        o[3] = pk2(b[2], b[3]);
        ((u32x4*)out)[i] = o;
    }
}

// ---------------------------------------------------------------------------
// fp32 -> bf16 convert + pack A into FRAGMENT ORDER.
// Chunk(p=2t+kh, wr, mf) = 1024 B = 64 lanes x 16 B, lane l holds
// A[mt*256 + wr*128 + mf*16 + (l&15)][t*64 + kh*32 + (l>>4)*8 .. +7].
// Offset (shorts) = mt*nsteps*16384 + p*8192 + wr*4096 + mf*512 + lane*8.
// In the GEMM each wave's 8 A-frag loads per phase are then fully coalesced
// dwordx4 register loads (no LDS for A at all).
// ---------------------------------------------------------------------------
__global__ __launch_bounds__(256)
void cvt_pack_a(const float* __restrict__ in, unsigned short* __restrict__ out, int K) {
    const int kg = K >> 3;          // 16B granules per row
    const int nsteps = K >> 6;
    const int ng = BT * kg;
    for (int gid = blockIdx.x * 256 + threadIdx.x; gid < ng; gid += gridDim.x * 256) {
        const int row = gid / kg;
        const int k8 = gid - row * kg;
        const int mt = row >> 8;
        const int wr = (row >> 7) & 1;
        const int mf = (row >> 4) & 7;
        const int lr = row & 15;
        const int t = k8 >> 3;
        const int kh = (k8 >> 2) & 1;
        const int g = k8 & 3;
        const int lane = g * 16 + lr;
        const int p = t * 2 + kh;
        const size_t off = (size_t)mt * nsteps * 16384 + (size_t)p * 8192
                         + wr * 4096 + mf * 512 + lane * 8;
        const float* src = in + (size_t)row * K + k8 * 8;
        const f32x4 lo = *(const f32x4*)src;
        const f32x4 hi = *(const f32x4*)(src + 4);
        u32x4 o;
        o[0] = pk2(lo[0], lo[1]);
        o[1] = pk2(lo[2], lo[3]);
        o[2] = pk2(hi[0], hi[1]);
        o[3] = pk2(hi[2], hi[3]);
        *(u32x4*)(out + off) = o;
    }
}

// ---------------------------------------------------------------------------
// 256x256 GEMM: A-fragments from GLOBAL (packed, register-resident, L1-hot);
// only B staged in LDS (4-region K-half ring, round-6 proven swizzle).
// C[m,v] = sum_k A[m,k] * W[v,k].  512 thr (8 waves 2Mx4N), wave tile 128x64.
// Per phase (K=32): 8 coalesced A-frag loads (next phase, ping-pong regs),
// 4 ds_read_b128 B-frags (region compile-time via 2-tile unroll), 2
// global_load_lds B-stage (region p+3), 32 MFMA, 1 barrier.  LDS reads/CU
// per phase drop 96 -> 32 (A duplication eliminated); LDS = 64 KB.
// Sync: B(p) staged at p-3 is always OLDER than A(p-1) issued at p-2, and
// the compiler's vmcnt wait before phase p-1's MFMAs (A-frag consumers)
// therefore guarantees B(p) landed before phase p's ds_reads — no manual
// in-loop vmcnt needed; prologue drains once with vmcnt(0).
// ---------------------------------------------------------------------------
#define FENCE() asm volatile("" ::: "memory")
#define BARRIER() do { FENCE(); __builtin_amdgcn_s_barrier(); FENCE(); } while (0)

#define BSTAGE(kh, t, r) do { if ((t) < nsteps) {                             \
    _Pragma("unroll")                                                         \
    for (int l_ = 0; l_ < 2; ++l_) {                                          \
        const int gi_ = (wave * 2 + l_) * 64 + lane;                          \
        const int rp_ = gi_ >> 3, sgi_ = gi_ & 7;                             \
        const int raw_ = sgi_ ^ (rp_ & 7);                                    \
        const int row_ = rp_ * 2 + (raw_ >> 2);                               \
        const int gk_ = raw_ & 3;                                             \
        const unsigned short* src_ = Wb + (size_t)row_ * K                    \
                  + ((size_t)(t) << 6) + (kh) * 32 + gk_ * 8;                 \
        unsigned short* dst_ = (unsigned short*)&lB[r][(wave * 2 + l_) * 512]; \
        __builtin_amdgcn_global_load_lds((AS1 const void*)src_,               \
                                         (AS3 void*)dst_, 16, 0, 0);          \
    } } } while (0)

#define PHASE_AR(RR, TT, KH, ACUR, ANXT) do {                                 \
    if ((KH) == 0 || (TT) + 1 < nsteps) {                                     \
        _Pragma("unroll")                                                     \
        for (int mf_ = 0; mf_ < 8; ++mf_)                                     \
            ANXT[mf_] = *(const s16x8*)(apre + mf_ * 512);                    \
    }                                                                         \
    apre += 8192;                                                             \
    s16x8 b_[4];                                                              \
    _Pragma("unroll")                                                         \
    for (int nf_ = 0; nf_ < 4; ++nf_) {                                       \
        const int row_ = wc * 64 + nf_ * 16 + (lane & 15);                    \
        const int raw_ = (row_ & 1) * 4 + (lane >> 4);                        \
        const int rp_ = row_ >> 1;                                            \
        b_[nf_] = *(const s16x8*)&lB[RR][rp_ * 64 + ((raw_ ^ (rp_ & 7)) << 3)]; \
    }                                                                         \
    BSTAGE(1 - (KH), (TT) + 1 + (KH), ((RR) + 3) & 3);                        \
    __builtin_amdgcn_s_setprio(1);                                            \
    _Pragma("unroll")                                                         \
    for (int mf_ = 0; mf_ < 8; ++mf_)                                         \
        _Pragma("unroll")                                                     \
        for (int nf_ = 0; nf_ < 4; ++nf_)                                     \
            acc[mf_][nf_] = __builtin_amdgcn_mfma_f32_16x16x32_bf16(          \
                ACUR[mf_], b_[nf_], acc[mf_][nf_], 0, 0, 0);                  \
    __builtin_amdgcn_s_setprio(0);                                            \
    BARRIER();                                                                \
} while (0)

__global__ __launch_bounds__(512, 2)
void gemm_ar(const unsigned short* __restrict__ Ap, const unsigned short* __restrict__ W,
             unsigned short* __restrict__ C, int K) {
    const int cpx = gridDim.x >> 3;
    const int braw = blockIdx.x;
    const int bid = (braw & 7) * cpx + (braw >> 3);   // bijective: grid % 8 == 0
    const int mt = bid & 7;       // m-inner: W-panel L2 reuse
    const int nt = bid >> 3;
    const int tid = threadIdx.x;
    const int lane = tid & 63;
    const int wave = tid >> 6;
    const int wr = wave >> 2;     // 0..1
    const int wc = wave & 3;      // 0..3

    __shared__ unsigned short lB[4][8192];   // 4 regions x 16 KB (B only)

    f32x4 acc[8][4];
    #pragma unroll
    for (int m = 0; m < 8; ++m)
        #pragma unroll
        for (int n = 0; n < 4; ++n)
            acc[m][n] = (f32x4){0.f, 0.f, 0.f, 0.f};

    const unsigned short* Wb = W + (size_t)(nt * 256) * K;
    const int nsteps = K >> 6;

    // per-wave packed-A cursor (phase 0), advances +8192 shorts per phase
    const unsigned short* apre = Ap + (size_t)mt * nsteps * 16384
                               + wr * 4096 + lane * 8;

    s16x8 a0[8], a1[8];

    // prologue: stage B for phases 0,1,2; load A(phase 0); full drain once
    BSTAGE(0, 0, 0);
    BSTAGE(1, 0, 1);
    BSTAGE(0, 1, 2);
    #pragma unroll
    for (int mf = 0; mf < 8; ++mf) a0[mf] = *(const s16x8*)(apre + mf * 512);
    apre += 8192;
    asm volatile("s_waitcnt vmcnt(0)" ::: "memory");
    BARRIER();

    for (int t = 0; t < nsteps; t += 2) {     // nsteps even (32 or 64)
        PHASE_AR(0, t, 0, a0, a1);
        PHASE_AR(1, t, 1, a1, a0);
        PHASE_AR(2, t + 1, 0, a0, a1);
        PHASE_AR(3, t + 1, 1, a1, a0);
    }

    // epilogue: C/D layout col = lane&15, row = (lane>>4)*4 + reg
    const int colb = nt * 256 + wc * 64 + (lane & 15);
    const int rowb = mt * 256 + wr * 128 + ((lane >> 4) << 2);
    #pragma unroll
    for (int m = 0; m < 8; ++m)
        #pragma unroll
        for (int n = 0; n < 4; ++n) {
            #pragma unroll
            for (int j = 0; j < 4; ++j) {
                const size_t r = (size_t)(rowb + m * 16 + j);
                C[r * VOC + colb + n * 16] = f2bf(acc[m][n][j]);
            }
        }
}

// ---------------------------------------------------------------------------
// Fallback GEMM (fp32 operands, reg-staged convert) — used only if ws too small.
// ---------------------------------------------------------------------------
__global__ __launch_bounds__(256, 2)
void gemm_bf16(const float* __restrict__ A, const float* __restrict__ W,
               unsigned short* __restrict__ C, int K) {
    const int bid = blockIdx.x;
    const int mt = bid & 15;
    const int nt = bid >> 4;
    const int tid = threadIdx.x;
    const int lane = tid & 63;
    const int wave = tid >> 6;
    const int wm = (wave >> 1) << 6;
    const int wn = (wave & 1) << 6;

    __shared__ unsigned short lds[2][2][128 * 64];

    f32x4 acc[4][4];
    #pragma unroll
    for (int m = 0; m < 4; ++m)
        #pragma unroll
        for (int n = 0; n < 4; ++n)
            acc[m][n] = (f32x4){0.f, 0.f, 0.f, 0.f};

    const float* Ab = A + (size_t)(mt * 128) * K;
    const float* Wb = W + (size_t)(nt * 128) * K;
    const int nsteps = K >> 6;

    f32x4 ra[4][2], rb[4][2];
    int rrow[4], rk16[4];
    #pragma unroll
    for (int it = 0; it < 4; ++it) {
        int idx = it * 256 + tid;
        rrow[it] = idx >> 3;
        rk16[it] = idx & 7;
    }

    auto load_regs = [&](int step) {
        const int kb = step << 6;
        #pragma unroll
        for (int it = 0; it < 4; ++it) {
            const float* pa = Ab + (size_t)rrow[it] * K + kb + rk16[it] * 8;
            const float* pw = Wb + (size_t)rrow[it] * K + kb + rk16[it] * 8;
            ra[it][0] = *(const f32x4*)pa;
            ra[it][1] = *(const f32x4*)(pa + 4);
            rb[it][0] = *(const f32x4*)pw;
            rb[it][1] = *(const f32x4*)(pw + 4);
        }
    };

    auto write_lds = [&](int buf) {
        #pragma unroll
        for (int it = 0; it < 4; ++it) {
            const int row = rrow[it];
            const int sw = rk16[it] ^ (row & 7);
            const int off = row * 64 + sw * 8;
            u32x4 pa, pw;
            pa[0] = pk2(ra[it][0][0], ra[it][0][1]);
            pa[1] = pk2(ra[it][0][2], ra[it][0][3]);
            pa[2] = pk2(ra[it][1][0], ra[it][1][1]);
            pa[3] = pk2(ra[it][1][2], ra[it][1][3]);
            pw[0] = pk2(rb[it][0][0], rb[it][0][1]);
            pw[1] = pk2(rb[it][0][2], rb[it][0][3]);
            pw[2] = pk2(rb[it][1][0], rb[it][1][1]);
            pw[3] = pk2(rb[it][1][2], rb[it][1][3]);
            *(u32x4*)&lds[buf][0][off] = pa;
            *(u32x4*)&lds[buf][1][off] = pw;
        }
    };

    auto compute = [&](int buf) {
        #pragma unroll
        for (int ks = 0; ks < 2; ++ks) {
            const int g = ks * 4 + (lane >> 4);
            const int rsel = lane & 15;
            s16x8 afr[4], bwr[4];
            #pragma unroll
            for (int m = 0; m < 4; ++m) {
                int row = wm + m * 16 + rsel;
                afr[m] = *(const s16x8*)&lds[buf][0][row * 64 + ((g ^ (row & 7)) * 8)];
            }
            #pragma unroll
            for (int n = 0; n < 4; ++n) {
                int row = wn + n * 16 + rsel;
                bwr[n] = *(const s16x8*)&lds[buf][1][row * 64 + ((g ^ (row & 7)) * 8)];
            }
            #pragma unroll
            for (int m = 0; m < 4; ++m)
                #pragma unroll
                for (int n = 0; n < 4; ++n)
                    acc[m][n] = __builtin_amdgcn_mfma_f32_16x16x32_bf16(
                        afr[m], bwr[n], acc[m][n], 0, 0, 0);
        }
    };

    load_regs(0);
    write_lds(0);
    __syncthreads();
    for (int s = 0; s < nsteps; ++s) {
        if (s + 1 < nsteps) load_regs(s + 1);
        compute(s & 1);
        if (s + 1 < nsteps) write_lds((s + 1) & 1);
        __syncthreads();
    }

    const int colb = nt * 128 + wn + (lane & 15);
    const int rowb = mt * 128 + wm + ((lane >> 4) << 2);
    #pragma unroll
    for (int m = 0; m < 4; ++m)
        #pragma unroll
        for (int n = 0; n < 4; ++n) {
            #pragma unroll
            for (int j = 0; j < 4; ++j) {
                int r = rowb + m * 16 + j;
                int c = colb + n * 16;
                C[(size_t)r * VOC + c] = f2bf(acc[m][n][j]);
            }
        }
}

// ---------------------------------------------------------------------------
// count kernel: n_non_ignore -> 1/n (or 0), and zero d_out (graph-replay safe)
// ---------------------------------------------------------------------------
__global__ void count_kernel(const int* __restrict__ label,
                             float* __restrict__ invn, float* __restrict__ out) {
    int tid = threadIdx.x;
    int c = 0;
    for (int i = tid; i < BT; i += 256) c += (label[i] != IGN) ? 1 : 0;
    #pragma unroll
    for (int o = 32; o > 0; o >>= 1) c += __shfl_xor(c, o);
    __shared__ int red[4];
    if ((tid & 63) == 0) red[tid >> 6] = c;
    __syncthreads();
    if (tid == 0) {
        int n = red[0] + red[1] + red[2] + red[3];
        invn[0] = (n > 0) ? (1.0f / (float)n) : 0.0f;
        out[0] = 0.0f;
    }
}

// ---------------------------------------------------------------------------
// JSD kernel: one block per token, 2 passes over both bf16 logit rows.
// Pass 1: online max+sumexp -> lse.  Pass 2: JSD terms -> atomicAdd.
// ---------------------------------------------------------------------------
__global__ __launch_bounds__(1024)
void jsd_kernel(const unsigned short* __restrict__ TL, const unsigned short* __restrict__ SL,
                const int* __restrict__ label, const float* __restrict__ invn,
                float* __restrict__ out) {
    const int b = blockIdx.x;
    const int tid = threadIdx.x;
    const unsigned short* tl = TL + (size_t)b * VOC;
    const unsigned short* sl = SL + (size_t)b * VOC;
    __shared__ float rmA[16], rsA[16], rmB[16], rsB[16];
    __shared__ float lse2[2];

    float mp = -3.0e38f, sp = 0.f, mq = -3.0e38f, sq = 0.f;
    for (int i = tid; i < VOC / 8; i += 1024) {
        s16x8 vt = *(const s16x8*)(tl + i * 8);
        s16x8 vs = *(const s16x8*)(sl + i * 8);
        #pragma unroll
        for (int j = 0; j < 8; ++j) {
            float x = bf2f((unsigned short)vt[j]);
            if (x > mp) { sp = sp * __expf(mp - x) + 1.0f; mp = x; }
            else        { sp += __expf(x - mp); }
            float y = bf2f((unsigned short)vs[j]);
            if (y > mq) { sq = sq * __expf(mq - y) + 1.0f; mq = y; }
            else        { sq += __expf(y - mq); }
        }
    }
    #pragma unroll
    for (int o = 32; o > 0; o >>= 1) {
        float om = __shfl_xor(mp, o), os = __shfl_xor(sp, o);
        float nm = fmaxf(mp, om);
        sp = sp * __expf(mp - nm) + os * __expf(om - nm);
        mp = nm;
        om = __shfl_xor(mq, o); os = __shfl_xor(sq, o);
        nm = fmaxf(mq, om);
        sq = sq * __expf(mq - nm) + os * __expf(om - nm);
        mq = nm;
    }
    if ((tid & 63) == 0) {
        rmA[tid >> 6] = mp; rsA[tid >> 6] = sp;
        rmB[tid >> 6] = mq; rsB[tid >> 6] = sq;
    }
    __syncthreads();
    if (tid == 0) {
        float m1 = rmA[0], s1 = 0.f, m2 = rmB[0], s2 = 0.f;
        for (int w = 1; w < 16; ++w) { m1 = fmaxf(m1, rmA[w]); m2 = fmaxf(m2, rmB[w]); }
        for (int w = 0; w < 16; ++w) {
            s1 += rsA[w] * __expf(rmA[w] - m1);
            s2 += rsB[w] * __expf(rmB[w] - m2);
        }
        lse2[0] = m1 + __logf(s1);
        lse2[1] = m2 + __logf(s2);
    }
    __syncthreads();
    const float lsep = lse2[0];
    const float lseq = lse2[1];

    float accj = 0.f;
    for (int i = tid; i < VOC / 8; i += 1024) {
        s16x8 vt = *(const s16x8*)(tl + i * 8);
        s16x8 vs = *(const s16x8*)(sl + i * 8);
        #pragma unroll
        for (int j = 0; j < 8; ++j) {
            float lp = bf2f((unsigned short)vt[j]) - lsep;
            float lq = bf2f((unsigned short)vs[j]) - lseq;
            float m0 = fmaxf(lp, lq);
            float e = __expf(-fabsf(lp - lq));
            float lm = m0 + __logf(0.5f * (1.0f + e));
            accj += 0.5f * (__expf(lp) * (lp - lm) + __expf(lq) * (lq - lm));
        }
    }
    #pragma unroll
    for (int o = 32; o > 0; o >>= 1) accj += __shfl_xor(accj, o);
    if ((tid & 63) == 0) rmA[tid >> 6] = accj;
    __syncthreads();
    if (tid == 0) {
        float a = 0.f;
        for (int w = 0; w < 16; ++w) a += rmA[w];
        if (label[b] != IGN) atomicAdd(out, a * invn[0]);
    }
}

extern "C" void kernel_launch(void* const* d_in, const int* in_sizes, int n_in,
                              void* d_out, int out_size, void* d_ws, size_t ws_size,
                              hipStream_t stream) {
    const float* s_in = (const float*)d_in[0];   // [BT, 2048]
    const float* t_in = (const float*)d_in[1];   // [BT, 4096]
    const float* Ws   = (const float*)d_in[2];   // [VOC, 2048]
    const float* Wt   = (const float*)d_in[3];   // [VOC, 4096]
    const int* label  = (const int*)d_in[4];     // [BT]
    float* out = (float*)d_out;

    const size_t L   = (size_t)BT * VOC;
    const size_t eWt = (size_t)VOC * 4096;
    const size_t eWs = (size_t)VOC * 2048;
    const size_t eAt = (size_t)BT * 4096;
    const size_t eAs = (size_t)BT * 2048;

    const size_t need_full = (2 * L + eWt + eWs + eAt + eAs) * sizeof(unsigned short) + 64;
    const size_t need_min  = 2 * L * sizeof(unsigned short) + 64;

    if (ws_size >= need_full) {
        unsigned short* logT = (unsigned short*)d_ws;
        unsigned short* logS = logT + L;
        unsigned short* Wtb  = logS + L;
        unsigned short* Wsb  = Wtb + eWt;
        unsigned short* Atb  = Wsb + eWs;   // packed A (teacher)
        unsigned short* Asb  = Atb + eAt;   // packed A (student)
        float* invn = (float*)(Asb + eAs);

        cvt_kernel<<<dim3(2048), dim3(256), 0, stream>>>(Wt, Wtb, (int)(eWt / 8));
        cvt_kernel<<<dim3(2048), dim3(256), 0, stream>>>(Ws, Wsb, (int)(eWs / 8));
        cvt_pack_a<<<dim3(1024), dim3(256), 0, stream>>>(t_in, Atb, 4096);
        cvt_pack_a<<<dim3(1024), dim3(256), 0, stream>>>(s_in, Asb, 2048);
        count_kernel<<<dim3(1), dim3(256), 0, stream>>>(label, invn, out);
        gemm_ar<<<dim3(8 * (VOC / 256)), dim3(512), 0, stream>>>(Atb, Wtb, logT, 4096);
        gemm_ar<<<dim3(8 * (VOC / 256)), dim3(512), 0, stream>>>(Asb, Wsb, logS, 2048);
        jsd_kernel<<<dim3(BT), dim3(1024), 0, stream>>>(logT, logS, label, invn, out);
    } else {
        if (ws_size < need_min) return;
        unsigned short* logT = (unsigned short*)d_ws;
        unsigned short* logS = logT + L;
        float* invn = (float*)(logS + L);

        count_kernel<<<dim3(1), dim3(256), 0, stream>>>(label, invn, out);
        gemm_bf16<<<dim3(16 * (VOC / 128)), dim3(256), 0, stream>>>(t_in, Wt, logT, 4096);
        gemm_bf16<<<dim3(16 * (VOC / 128)), dim3(256), 0, stream>>>(s_in, Ws, logS, 2048);
        jsd_kernel<<<dim3(BT), dim3(1024), 0, stream>>>(logT, logS, label, invn, out);
    }
}

// Round 9
// 1129.491 us; speedup vs baseline: 2.2621x; 2.2621x over previous
//
#include <hip/hip_runtime.h>
#include <hip/hip_bf16.h>

#define BT 2048
#define VOC 32000
#define IGN (-100)

typedef __attribute__((ext_vector_type(4))) float f32x4;
typedef __attribute__((ext_vector_type(8))) short s16x8;
typedef __attribute__((ext_vector_type(4))) unsigned int u32x4;

#define AS1 __attribute__((address_space(1)))
#define AS3 __attribute__((address_space(3)))

__device__ __forceinline__ unsigned short f2bf(float f) {
    union { __hip_bfloat16 h; unsigned short u; } c;
    c.h = __float2bfloat16(f);
    return c.u;
}
__device__ __forceinline__ float bf2f(unsigned short u) {
    union { unsigned int u; float f; } c;
    c.u = ((unsigned int)u) << 16;
    return c.f;
}
__device__ __forceinline__ unsigned int pk2(float a, float b) {
    return (unsigned int)f2bf(a) | ((unsigned int)f2bf(b) << 16);
}

// ---------------------------------------------------------------------------
// fp32 -> bf16 pre-convert, row-major
// ---------------------------------------------------------------------------
__global__ __launch_bounds__(256)
void cvt_kernel(const float* __restrict__ in, unsigned short* __restrict__ out, int n8) {
    for (int i = blockIdx.x * 256 + threadIdx.x; i < n8; i += gridDim.x * 256) {
        f32x4 a = ((const f32x4*)in)[2 * i];
        f32x4 b = ((const f32x4*)in)[2 * i + 1];
        u32x4 o;
        o[0] = pk2(a[0], a[1]);
        o[1] = pk2(a[2], a[3]);
        o[2] = pk2(b[0], b[1]);
        o[3] = pk2(b[2], b[3]);
        ((u32x4*)out)[i] = o;
    }
}

// ---------------------------------------------------------------------------
// 256x256 GEMM (bf16 operands), 4-region K-half ring, 1 barrier per phase.
// EXACT round-6 schedule (proven 45% MfmaUtil / 518us teacher) with a VALU
// diet only:
//  - t-loop unrolled x2 -> ring regions are compile-time constants
//  - 12 ds_read byte-offsets precomputed once (region-invariant); per-phase
//    reads are vaddr + compile-time region offset (folds to offset:imm)
//  - 4 staging global cursors precomputed once with the inverse swizzle
//    baked in; advance +256B per iteration; per-phase (tile,khalf) deltas
//    are literal byte immediates (192/256/320/384)
// Schedule recap: phase p consumes region p%4, stages data for p+3 into
// region (p+3)%4 (freed at p-1 -> WAR-safe across >=1 barrier); end-of-phase
// vmcnt(8) keeps 2 phases of gloads in flight and guarantees the p+1 region
// landed (FIFO). Tail ladder identical to round 6.
// ---------------------------------------------------------------------------
#define FENCE() asm volatile("" ::: "memory")
#define BARRIER() do { FENCE(); __builtin_amdgcn_s_barrier(); FENCE(); } while (0)
#define WAIT_LGKM0() do { asm volatile("s_waitcnt lgkmcnt(0)" ::: "memory"); \
                          __builtin_amdgcn_sched_barrier(0); } while (0)

// one phase: R = region (compile-time), TT = tile idx, KH = k-half,
// DELTA = literal byte offset of the staged (tile,khalf) from the cursor,
// STc = stage guard condition
#define PHASE(R, TT, KH, DELTA) do {                                          \
    s16x8 a_[8], b_[4];                                                       \
    _Pragma("unroll")                                                         \
    for (int mf_ = 0; mf_ < 8; ++mf_)                                         \
        a_[mf_] = *(const s16x8*)((const char*)&lA[R][0] + offA[mf_]);        \
    _Pragma("unroll")                                                         \
    for (int nf_ = 0; nf_ < 4; ++nf_)                                         \
        b_[nf_] = *(const s16x8*)((const char*)&lB[R][0] + offB[nf_]);        \
    if ((KH) == 0 ? ((TT) + 1 < nsteps) : ((TT) + 2 < nsteps)) {              \
        _Pragma("unroll")                                                     \
        for (int l_ = 0; l_ < 2; ++l_) {                                      \
            __builtin_amdgcn_global_load_lds(                                 \
                (AS1 const void*)((const char*)sA[l_] + (DELTA)),             \
                (AS3 void*)&lA[((R) + 3) & 3][(wave * 2 + l_) * 512], 16, 0, 0); \
            __builtin_amdgcn_global_load_lds(                                 \
                (AS1 const void*)((const char*)sB[l_] + (DELTA)),             \
                (AS3 void*)&lB[((R) + 3) & 3][(wave * 2 + l_) * 512], 16, 0, 0); \
        }                                                                     \
    }                                                                         \
    WAIT_LGKM0();                                                             \
    __builtin_amdgcn_s_setprio(1);                                            \
    _Pragma("unroll")                                                         \
    for (int mf_ = 0; mf_ < 8; ++mf_)                                         \
        _Pragma("unroll")                                                     \
        for (int nf_ = 0; nf_ < 4; ++nf_)                                     \
            acc[mf_][nf_] = __builtin_amdgcn_mfma_f32_16x16x32_bf16(          \
                a_[mf_], b_[nf_], acc[mf_][nf_], 0, 0, 0);                    \
    __builtin_amdgcn_s_setprio(0);                                            \
    if ((KH) == 0) {                                                          \
        if ((TT) + 1 < nsteps) asm volatile("s_waitcnt vmcnt(8)" ::: "memory"); \
        else                   asm volatile("s_waitcnt vmcnt(0)" ::: "memory"); \
    } else {                                                                  \
        if ((TT) + 2 < nsteps)      asm volatile("s_waitcnt vmcnt(8)" ::: "memory"); \
        else if ((TT) + 1 < nsteps) asm volatile("s_waitcnt vmcnt(4)" ::: "memory"); \
        else                        asm volatile("s_waitcnt vmcnt(0)" ::: "memory"); \
    }                                                                         \
    BARRIER();                                                                \
} while (0)

__global__ __launch_bounds__(512, 2)
void gemm2p(const unsigned short* __restrict__ A, const unsigned short* __restrict__ W,
            unsigned short* __restrict__ C, int K) {
    const int cpx = gridDim.x >> 3;
    const int braw = blockIdx.x;
    const int bid = (braw & 7) * cpx + (braw >> 3);   // bijective: grid % 8 == 0
    const int mt = bid & 7;       // m-inner: W-panel L2 reuse
    const int nt = bid >> 3;
    const int tid = threadIdx.x;
    const int lane = tid & 63;
    const int wave = tid >> 6;
    const int wr = wave >> 2;     // 0..1
    const int wc = wave & 3;      // 0..3

    __shared__ unsigned short lA[4][8192];   // 4 regions: 256 rows x 32 k each
    __shared__ unsigned short lB[4][8192];

    f32x4 acc[8][4];
    #pragma unroll
    for (int m = 0; m < 8; ++m)
        #pragma unroll
        for (int n = 0; n < 4; ++n)
            acc[m][n] = (f32x4){0.f, 0.f, 0.f, 0.f};

    const unsigned short* Ab = A + (size_t)(mt * 256) * K;
    const unsigned short* Wb = W + (size_t)(nt * 256) * K;
    const int nsteps = K >> 6;

    // ---- precomputed ds_read byte offsets (region-invariant) ----
    int offA[8], offB[4];
    #pragma unroll
    for (int mf = 0; mf < 8; ++mf) {
        const int row = wr * 128 + mf * 16 + (lane & 15);
        const int raw = (row & 1) * 4 + (lane >> 4);
        const int rp = row >> 1;
        offA[mf] = rp * 128 + ((raw ^ (rp & 7)) << 4);   // bytes
    }
    #pragma unroll
    for (int nf = 0; nf < 4; ++nf) {
        const int row = wc * 64 + nf * 16 + (lane & 15);
        const int raw = (row & 1) * 4 + (lane >> 4);
        const int rp = row >> 1;
        offB[nf] = rp * 128 + ((raw ^ (rp & 7)) << 4);   // bytes
    }

    // ---- precomputed staging cursors (inverse swizzle baked in) ----
    // src(tile t, khalf kh) = cursor + t*128B + kh*64B
    const unsigned short* sA[2];
    const unsigned short* sB[2];
    #pragma unroll
    for (int l = 0; l < 2; ++l) {
        const int gi = (wave * 2 + l) * 64 + lane;
        const int rp = gi >> 3, sgi = gi & 7;
        const int raw = sgi ^ (rp & 7);
        const int row = rp * 2 + (raw >> 2);
        const int gk = raw & 3;
        sA[l] = Ab + (size_t)row * K + gk * 8;
        sB[l] = Wb + (size_t)row * K + gk * 8;
    }

    // prologue: stage (t0,k0)->R0 @ +0B, (t0,k1)->R1 @ +64B, (t1,k0)->R2 @ +128B
    #pragma unroll
    for (int l = 0; l < 2; ++l) {
        __builtin_amdgcn_global_load_lds((AS1 const void*)sA[l],
            (AS3 void*)&lA[0][(wave * 2 + l) * 512], 16, 0, 0);
        __builtin_amdgcn_global_load_lds((AS1 const void*)sB[l],
            (AS3 void*)&lB[0][(wave * 2 + l) * 512], 16, 0, 0);
    }
    #pragma unroll
    for (int l = 0; l < 2; ++l) {
        __builtin_amdgcn_global_load_lds((AS1 const void*)((const char*)sA[l] + 64),
            (AS3 void*)&lA[1][(wave * 2 + l) * 512], 16, 0, 0);
        __builtin_amdgcn_global_load_lds((AS1 const void*)((const char*)sB[l] + 64),
            (AS3 void*)&lB[1][(wave * 2 + l) * 512], 16, 0, 0);
    }
    #pragma unroll
    for (int l = 0; l < 2; ++l) {
        __builtin_amdgcn_global_load_lds((AS1 const void*)((const char*)sA[l] + 128),
            (AS3 void*)&lA[2][(wave * 2 + l) * 512], 16, 0, 0);
        __builtin_amdgcn_global_load_lds((AS1 const void*)((const char*)sB[l] + 128),
            (AS3 void*)&lB[2][(wave * 2 + l) * 512], 16, 0, 0);
    }
    asm volatile("s_waitcnt vmcnt(8)" ::: "memory");
    BARRIER();

    for (int t = 0; t < nsteps; t += 2) {     // nsteps even (32 or 64)
        // phase (t,0): consume R0, stage (t+1,k1) @ +192B -> R3
        PHASE(0, t, 0, 192);
        // phase (t,1): consume R1, stage (t+2,k0) @ +256B -> R0
        PHASE(1, t, 1, 256);
        // phase (t+1,0): consume R2, stage (t+2,k1) @ +320B -> R1
        PHASE(2, t + 1, 0, 320);
        // phase (t+1,1): consume R3, stage (t+3,k0) @ +384B -> R2
        PHASE(3, t + 1, 1, 384);
        sA[0] += 128; sA[1] += 128;
        sB[0] += 128; sB[1] += 128;
    }

    // epilogue: C/D layout col = lane&15, row = (lane>>4)*4 + reg
    const int colb = nt * 256 + wc * 64 + (lane & 15);
    const int rowb = mt * 256 + wr * 128 + ((lane >> 4) << 2);
    #pragma unroll
    for (int m = 0; m < 8; ++m)
        #pragma unroll
        for (int n = 0; n < 4; ++n) {
            #pragma unroll
            for (int j = 0; j < 4; ++j) {
                const size_t r = (size_t)(rowb + m * 16 + j);
                C[r * VOC + colb + n * 16] = f2bf(acc[m][n][j]);
            }
        }
}

// ---------------------------------------------------------------------------
// Fallback GEMM (fp32 operands, reg-staged convert) — used only if ws too small.
// ---------------------------------------------------------------------------
__global__ __launch_bounds__(256, 2)
void gemm_bf16(const float* __restrict__ A, const float* __restrict__ W,
               unsigned short* __restrict__ C, int K) {
    const int bid = blockIdx.x;
    const int mt = bid & 15;
    const int nt = bid >> 4;
    const int tid = threadIdx.x;
    const int lane = tid & 63;
    const int wave = tid >> 6;
    const int wm = (wave >> 1) << 6;
    const int wn = (wave & 1) << 6;

    __shared__ unsigned short lds[2][2][128 * 64];

    f32x4 acc[4][4];
    #pragma unroll
    for (int m = 0; m < 4; ++m)
        #pragma unroll
        for (int n = 0; n < 4; ++n)
            acc[m][n] = (f32x4){0.f, 0.f, 0.f, 0.f};

    const float* Ab = A + (size_t)(mt * 128) * K;
    const float* Wb = W + (size_t)(nt * 128) * K;
    const int nsteps = K >> 6;

    f32x4 ra[4][2], rb[4][2];
    int rrow[4], rk16[4];
    #pragma unroll
    for (int it = 0; it < 4; ++it) {
        int idx = it * 256 + tid;
        rrow[it] = idx >> 3;
        rk16[it] = idx & 7;
    }

    auto load_regs = [&](int step) {
        const int kb = step << 6;
        #pragma unroll
        for (int it = 0; it < 4; ++it) {
            const float* pa = Ab + (size_t)rrow[it] * K + kb + rk16[it] * 8;
            const float* pw = Wb + (size_t)rrow[it] * K + kb + rk16[it] * 8;
            ra[it][0] = *(const f32x4*)pa;
            ra[it][1] = *(const f32x4*)(pa + 4);
            rb[it][0] = *(const f32x4*)pw;
            rb[it][1] = *(const f32x4*)(pw + 4);
        }
    };

    auto write_lds = [&](int buf) {
        #pragma unroll
        for (int it = 0; it < 4; ++it) {
            const int row = rrow[it];
            const int sw = rk16[it] ^ (row & 7);
            const int off = row * 64 + sw * 8;
            u32x4 pa, pw;
            pa[0] = pk2(ra[it][0][0], ra[it][0][1]);
            pa[1] = pk2(ra[it][0][2], ra[it][0][3]);
            pa[2] = pk2(ra[it][1][0], ra[it][1][1]);
            pa[3] = pk2(ra[it][1][2], ra[it][1][3]);
            pw[0] = pk2(rb[it][0][0], rb[it][0][1]);
            pw[1] = pk2(rb[it][0][2], rb[it][0][3]);
            pw[2] = pk2(rb[it][1][0], rb[it][1][1]);
            pw[3] = pk2(rb[it][1][2], rb[it][1][3]);
            *(u32x4*)&lds[buf][0][off] = pa;
            *(u32x4*)&lds[buf][1][off] = pw;
        }
    };

    auto compute = [&](int buf) {
        #pragma unroll
        for (int ks = 0; ks < 2; ++ks) {
            const int g = ks * 4 + (lane >> 4);
            const int rsel = lane & 15;
            s16x8 afr[4], bwr[4];
            #pragma unroll
            for (int m = 0; m < 4; ++m) {
                int row = wm + m * 16 + rsel;
                afr[m] = *(const s16x8*)&lds[buf][0][row * 64 + ((g ^ (row & 7)) * 8)];
            }
            #pragma unroll
            for (int n = 0; n < 4; ++n) {
                int row = wn + n * 16 + rsel;
                bwr[n] = *(const s16x8*)&lds[buf][1][row * 64 + ((g ^ (row & 7)) * 8)];
            }
            #pragma unroll
            for (int m = 0; m < 4; ++m)
                #pragma unroll
                for (int n = 0; n < 4; ++n)
                    acc[m][n] = __builtin_amdgcn_mfma_f32_16x16x32_bf16(
                        afr[m], bwr[n], acc[m][n], 0, 0, 0);
        }
    };

    load_regs(0);
    write_lds(0);
    __syncthreads();
    for (int s = 0; s < nsteps; ++s) {
        if (s + 1 < nsteps) load_regs(s + 1);
        compute(s & 1);
        if (s + 1 < nsteps) write_lds((s + 1) & 1);
        __syncthreads();
    }

    const int colb = nt * 128 + wn + (lane & 15);
    const int rowb = mt * 128 + wm + ((lane >> 4) << 2);
    #pragma unroll
    for (int m = 0; m < 4; ++m)
        #pragma unroll
        for (int n = 0; n < 4; ++n) {
            #pragma unroll
            for (int j = 0; j < 4; ++j) {
                int r = rowb + m * 16 + j;
                int c = colb + n * 16;
                C[(size_t)r * VOC + c] = f2bf(acc[m][n][j]);
            }
        }
}

// ---------------------------------------------------------------------------
// count kernel: n_non_ignore -> 1/n (or 0), and zero d_out (graph-replay safe)
// ---------------------------------------------------------------------------
__global__ void count_kernel(const int* __restrict__ label,
                             float* __restrict__ invn, float* __restrict__ out) {
    int tid = threadIdx.x;
    int c = 0;
    for (int i = tid; i < BT; i += 256) c += (label[i] != IGN) ? 1 : 0;
    #pragma unroll
    for (int o = 32; o > 0; o >>= 1) c += __shfl_xor(c, o);
    __shared__ int red[4];
    if ((tid & 63) == 0) red[tid >> 6] = c;
    __syncthreads();
    if (tid == 0) {
        int n = red[0] + red[1] + red[2] + red[3];
        invn[0] = (n > 0) ? (1.0f / (float)n) : 0.0f;
        out[0] = 0.0f;
    }
}

// ---------------------------------------------------------------------------
// JSD kernel: one block per token, 2 passes over both bf16 logit rows.
// Pass 1: online max+sumexp -> lse.  Pass 2: JSD terms -> atomicAdd.
// ---------------------------------------------------------------------------
__global__ __launch_bounds__(1024)
void jsd_kernel(const unsigned short* __restrict__ TL, const unsigned short* __restrict__ SL,
                const int* __restrict__ label, const float* __restrict__ invn,
                float* __restrict__ out) {
    const int b = blockIdx.x;
    const int tid = threadIdx.x;
    const unsigned short* tl = TL + (size_t)b * VOC;
    const unsigned short* sl = SL + (size_t)b * VOC;
    __shared__ float rmA[16], rsA[16], rmB[16], rsB[16];
    __shared__ float lse2[2];

    float mp = -3.0e38f, sp = 0.f, mq = -3.0e38f, sq = 0.f;
    for (int i = tid; i < VOC / 8; i += 1024) {
        s16x8 vt = *(const s16x8*)(tl + i * 8);
        s16x8 vs = *(const s16x8*)(sl + i * 8);
        #pragma unroll
        for (int j = 0; j < 8; ++j) {
            float x = bf2f((unsigned short)vt[j]);
            if (x > mp) { sp = sp * __expf(mp - x) + 1.0f; mp = x; }
            else        { sp += __expf(x - mp); }
            float y = bf2f((unsigned short)vs[j]);
            if (y > mq) { sq = sq * __expf(mq - y) + 1.0f; mq = y; }
            else        { sq += __expf(y - mq); }
        }
    }
    #pragma unroll
    for (int o = 32; o > 0; o >>= 1) {
        float om = __shfl_xor(mp, o), os = __shfl_xor(sp, o);
        float nm = fmaxf(mp, om);
        sp = sp * __expf(mp - nm) + os * __expf(om - nm);
        mp = nm;
        om = __shfl_xor(mq, o); os = __shfl_xor(sq, o);
        nm = fmaxf(mq, om);
        sq = sq * __expf(mq - nm) + os * __expf(om - nm);
        mq = nm;
    }
    if ((tid & 63) == 0) {
        rmA[tid >> 6] = mp; rsA[tid >> 6] = sp;
        rmB[tid >> 6] = mq; rsB[tid >> 6] = sq;
    }
    __syncthreads();
    if (tid == 0) {
        float m1 = rmA[0], s1 = 0.f, m2 = rmB[0], s2 = 0.f;
        for (int w = 1; w < 16; ++w) { m1 = fmaxf(m1, rmA[w]); m2 = fmaxf(m2, rmB[w]); }
        for (int w = 0; w < 16; ++w) {
            s1 += rsA[w] * __expf(rmA[w] - m1);
            s2 += rsB[w] * __expf(rmB[w] - m2);
        }
        lse2[0] = m1 + __logf(s1);
        lse2[1] = m2 + __logf(s2);
    }
    __syncthreads();
    const float lsep = lse2[0];
    const float lseq = lse2[1];

    float accj = 0.f;
    for (int i = tid; i < VOC / 8; i += 1024) {
        s16x8 vt = *(const s16x8*)(tl + i * 8);
        s16x8 vs = *(const s16x8*)(sl + i * 8);
        #pragma unroll
        for (int j = 0; j < 8; ++j) {
            float lp = bf2f((unsigned short)vt[j]) - lsep;
            float lq = bf2f((unsigned short)vs[j]) - lseq;
            float m0 = fmaxf(lp, lq);
            float e = __expf(-fabsf(lp - lq));
            float lm = m0 + __logf(0.5f * (1.0f + e));
            accj += 0.5f * (__expf(lp) * (lp - lm) + __expf(lq) * (lq - lm));
        }
    }
    #pragma unroll
    for (int o = 32; o > 0; o >>= 1) accj += __shfl_xor(accj, o);
    if ((tid & 63) == 0) rmA[tid >> 6] = accj;
    __syncthreads();
    if (tid == 0) {
        float a = 0.f;
        for (int w = 0; w < 16; ++w) a += rmA[w];
        if (label[b] != IGN) atomicAdd(out, a * invn[0]);
    }
}

extern "C" void kernel_launch(void* const* d_in, const int* in_sizes, int n_in,
                              void* d_out, int out_size, void* d_ws, size_t ws_size,
                              hipStream_t stream) {
    const float* s_in = (const float*)d_in[0];   // [BT, 2048]
    const float* t_in = (const float*)d_in[1];   // [BT, 4096]
    const float* Ws   = (const float*)d_in[2];   // [VOC, 2048]
    const float* Wt   = (const float*)d_in[3];   // [VOC, 4096]
    const int* label  = (const int*)d_in[4];     // [BT]
    float* out = (float*)d_out;

    const size_t L   = (size_t)BT * VOC;
    const size_t eWt = (size_t)VOC * 4096;
    const size_t eWs = (size_t)VOC * 2048;
    const size_t eAt = (size_t)BT * 4096;
    const size_t eAs = (size_t)BT * 2048;

    const size_t need_full = (2 * L + eWt + eWs + eAt + eAs) * sizeof(unsigned short) + 64;
    const size_t need_min  = 2 * L * sizeof(unsigned short) + 64;

    if (ws_size >= need_full) {
        unsigned short* logT = (unsigned short*)d_ws;
        unsigned short* logS = logT + L;
        unsigned short* Wtb  = logS + L;
        unsigned short* Wsb  = Wtb + eWt;
        unsigned short* Atb  = Wsb + eWs;
        unsigned short* Asb  = Atb + eAt;
        float* invn = (float*)(Asb + eAs);

        cvt_kernel<<<dim3(2048), dim3(256), 0, stream>>>(Wt, Wtb, (int)(eWt / 8));
        cvt_kernel<<<dim3(2048), dim3(256), 0, stream>>>(Ws, Wsb, (int)(eWs / 8));
        cvt_kernel<<<dim3(1024), dim3(256), 0, stream>>>(t_in, Atb, (int)(eAt / 8));
        cvt_kernel<<<dim3(1024), dim3(256), 0, stream>>>(s_in, Asb, (int)(eAs / 8));
        count_kernel<<<dim3(1), dim3(256), 0, stream>>>(label, invn, out);
        gemm2p<<<dim3(8 * (VOC / 256)), dim3(512), 0, stream>>>(Atb, Wtb, logT, 4096);
        gemm2p<<<dim3(8 * (VOC / 256)), dim3(512), 0, stream>>>(Asb, Wsb, logS, 2048);
        jsd_kernel<<<dim3(BT), dim3(1024), 0, stream>>>(logT, logS, label, invn, out);
    } else {
        if (ws_size < need_min) return;
        unsigned short* logT = (unsigned short*)d_ws;
        unsigned short* logS = logT + L;
        float* invn = (float*)(logS + L);

        count_kernel<<<dim3(1), dim3(256), 0, stream>>>(label, invn, out);
        gemm_bf16<<<dim3(16 * (VOC / 128)), dim3(256), 0, stream>>>(t_in, Wt, logT, 4096);
        gemm_bf16<<<dim3(16 * (VOC / 128)), dim3(256), 0, stream>>>(s_in, Ws, logS, 2048);
        jsd_kernel<<<dim3(BT), dim3(1024), 0, stream>>>(logT, logS, label, invn, out);
    }
}